// Round 1
// baseline (236.265 us; speedup 1.0000x reference)
//
#include <hip/hip_runtime.h>
#include <hip/hip_bf16.h>

// ---- types ----
typedef float  f32x4  __attribute__((ext_vector_type(4)));
typedef __bf16 bf16x8 __attribute__((ext_vector_type(8)));
typedef __bf16 bf16x4 __attribute__((ext_vector_type(4)));

#define T_SEQ   2048
#define HIDDEN  2048
#define NH      32
#define NKV     4
#define HD      64
#define QSZ     2048
#define KVSZ    256
#define QKVN    2560
#define WINDOW  1024
#define SCALE   0.125f

// ---------------- convert f32 -> bf16 (vectorized) ----------------
__global__ __launch_bounds__(256) void cvt_f32_bf16(const float4* __restrict__ in,
                                                    bf16x4* __restrict__ out) {
    int id = blockIdx.x * 256 + threadIdx.x;
    float4 v = in[id];
    bf16x4 o;
    o[0] = (__bf16)v.x; o[1] = (__bf16)v.y; o[2] = (__bf16)v.z; o[3] = (__bf16)v.w;
    out[id] = o;
}

// ---------------- transpose f32 [Rin][Cin] -> bf16 [Cin][Rin] ----------------
__global__ __launch_bounds__(256) void transpose_f32_bf16(const float* __restrict__ in,
                                                          __bf16* __restrict__ out,
                                                          int Rin, int Cin) {
    __shared__ float tile[32][33];
    int r = threadIdx.x >> 5;     // 0..7
    int c = threadIdx.x & 31;     // 0..31
    int ri = blockIdx.y * 32, ci = blockIdx.x * 32;
    #pragma unroll
    for (int i = 0; i < 4; i++)
        tile[r + i*8][c] = in[(size_t)(ri + r + i*8) * Cin + ci + c];
    __syncthreads();
    #pragma unroll
    for (int i = 0; i < 4; i++)
        out[(size_t)(ci + r + i*8) * Rin + ri + c] = (__bf16)tile[c][r + i*8];
}

// ---------------- GEMM: C[M][N] = A[M][K] * Bt[N][K]^T  (bf16 in, fp32 acc) ----------------
template<int WRITE_BF16>
__global__ __launch_bounds__(256) void gemm_bt(const __bf16* __restrict__ A,
                                               const __bf16* __restrict__ Bt,
                                               void* __restrict__ Cout,
                                               int M, int N, int K) {
    __shared__ __align__(16) __bf16 Asm[128][72];
    __shared__ __align__(16) __bf16 Bsm[128][72];
    const int tid = threadIdx.x;
    const int wid = tid >> 6;
    const int l   = tid & 63;
    const int lg  = l >> 4;       // 0..3
    const int ll  = l & 15;       // 0..15
    const int wm  = wid >> 1, wn = wid & 1;
    const int bm  = blockIdx.y * 128, bn = blockIdx.x * 128;

    f32x4 acc[4][4];
    #pragma unroll
    for (int i = 0; i < 4; i++)
        #pragma unroll
        for (int j = 0; j < 4; j++)
            acc[i][j] = (f32x4){0.f, 0.f, 0.f, 0.f};

    const int rowA = tid >> 3;    // 0..31
    const int segA = tid & 7;     // 0..7

    for (int k0 = 0; k0 < K; k0 += 64) {
        #pragma unroll
        for (int c = 0; c < 4; c++) {
            int row = c * 32 + rowA;
            bf16x8 av = *reinterpret_cast<const bf16x8*>(A  + (size_t)(bm + row) * K + k0 + segA * 8);
            *reinterpret_cast<bf16x8*>(&Asm[row][segA * 8]) = av;
            bf16x8 bv = *reinterpret_cast<const bf16x8*>(Bt + (size_t)(bn + row) * K + k0 + segA * 8);
            *reinterpret_cast<bf16x8*>(&Bsm[row][segA * 8]) = bv;
        }
        __syncthreads();
        #pragma unroll
        for (int ss = 0; ss < 2; ss++) {
            bf16x8 af[4], bfr[4];
            #pragma unroll
            for (int mi = 0; mi < 4; mi++)
                af[mi] = *reinterpret_cast<const bf16x8*>(&Asm[wm*64 + mi*16 + ll][ss*32 + lg*8]);
            #pragma unroll
            for (int ni = 0; ni < 4; ni++)
                bfr[ni] = *reinterpret_cast<const bf16x8*>(&Bsm[wn*64 + ni*16 + ll][ss*32 + lg*8]);
            #pragma unroll
            for (int mi = 0; mi < 4; mi++)
                #pragma unroll
                for (int ni = 0; ni < 4; ni++)
                    acc[mi][ni] = __builtin_amdgcn_mfma_f32_16x16x32_bf16(af[mi], bfr[ni], acc[mi][ni], 0, 0, 0);
        }
        __syncthreads();
    }

    // epilogue: D row=(lg*4+r), col=ll within each 16x16 frag
    #pragma unroll
    for (int mi = 0; mi < 4; mi++) {
        #pragma unroll
        for (int ni = 0; ni < 4; ni++) {
            #pragma unroll
            for (int r = 0; r < 4; r++) {
                int row = bm + wm*64 + mi*16 + lg*4 + r;
                int col = bn + wn*64 + ni*16 + ll;
                if (WRITE_BF16)
                    ((__bf16*)Cout)[(size_t)row * N + col] = (__bf16)acc[mi][ni][r];
                else
                    ((float*)Cout)[(size_t)row * N + col] = acc[mi][ni][r];
            }
        }
    }
}

// ---------------- RoPE + split qkv -> q(scaled), k, v ----------------
__global__ __launch_bounds__(256) void rope_split(const __bf16* __restrict__ qkv,
                                                  const int* __restrict__ pos,
                                                  __bf16* __restrict__ q,
                                                  __bf16* __restrict__ k,
                                                  __bf16* __restrict__ v) {
    int id = blockIdx.x * 256 + threadIdx.x;   // T_SEQ * 1280 total
    int row  = id / 1280;
    int slot = id % 1280;
    if (slot < 1152) {
        bool isq = slot < 1024;
        int s2 = isq ? slot : slot - 1024;
        int head = s2 >> 5, f = s2 & 31;
        const __bf16* src;
        __bf16* dst;
        if (isq) {
            src = qkv + (size_t)row * QKVN + head * 64 + f;
            dst = q   + (size_t)row * QSZ  + head * 64 + f;
        } else {
            src = qkv + (size_t)row * QKVN + QSZ + head * 64 + f;
            dst = k   + (size_t)row * KVSZ + head * 64 + f;
        }
        float x1 = (float)src[0], x2 = (float)src[32];
        float p = (float)pos[row];
        float ifr = powf(1.0e6f, -(float)f * (1.0f / 32.0f));
        float ang = p * ifr;
        float sn, cs;
        sincosf(ang, &sn, &cs);
        float o1 = x1 * cs - x2 * sn;
        float o2 = x2 * cs + x1 * sn;
        if (isq) { o1 *= SCALE; o2 *= SCALE; }
        dst[0]  = (__bf16)o1;
        dst[32] = (__bf16)o2;
    } else {
        int idx = (slot - 1152) * 2;           // 0..254 step 2
        v[(size_t)row * KVSZ + idx]     = qkv[(size_t)row * QKVN + QSZ + KVSZ + idx];
        v[(size_t)row * KVSZ + idx + 1] = qkv[(size_t)row * QKVN + QSZ + KVSZ + idx + 1];
    }
}

// ---------------- sliding-window GQA flash attention ----------------
// grid: (T/64, NH); block 256 = 4 waves; wave w handles q rows [qb*64+w*16, +16)
__global__ __launch_bounds__(256) void attn_kernel(const __bf16* __restrict__ qg,
                                                   const __bf16* __restrict__ kgl,
                                                   const __bf16* __restrict__ vgl,
                                                   __bf16* __restrict__ og) {
    const int qb  = blockIdx.x;
    const int h   = blockIdx.y;
    const int kvh = h >> 3;          // NH/NKV = 8
    const int tid = threadIdx.x;
    const int wid = tid >> 6;
    const int l   = tid & 63;
    const int lg  = l >> 4;
    const int ll  = l & 15;
    const int i0  = qb * 64;
    const int qrow_w = i0 + wid * 16;

    __shared__ __align__(16) __bf16 Ksm[32][72];
    __shared__ __align__(16) __bf16 Vts[64][40];
    __shared__ __align__(16) __bf16 Psm[4][16][40];

    // Q fragments (held across KV loop)
    bf16x8 qf[2];
    {
        const __bf16* qp = qg + (size_t)(qrow_w + ll) * QSZ + h * 64 + lg * 8;
        qf[0] = *reinterpret_cast<const bf16x8*>(qp);
        qf[1] = *reinterpret_cast<const bf16x8*>(qp + 32);
    }

    f32x4 o[4];
    #pragma unroll
    for (int dn = 0; dn < 4; dn++) o[dn] = (f32x4){0.f, 0.f, 0.f, 0.f};
    float m_run[4], l_run[4];
    #pragma unroll
    for (int r = 0; r < 4; r++) { m_run[r] = -1e30f; l_run[r] = 0.f; }

    int jlo = i0 - (WINDOW - 1); if (jlo < 0) jlo = 0;
    int t0 = (jlo >> 5) << 5;
    int tend = i0 + 64;

    for (int t = t0; t < tend; t += 32) {
        // stage K tile [32][64] and V^T tile [64][32]
        {
            int row = tid >> 3, seg = tid & 7;
            const __bf16* kp = kgl + (size_t)(t + row) * KVSZ + kvh * 64 + seg * 8;
            bf16x8 kv = *reinterpret_cast<const bf16x8*>(kp);
            *reinterpret_cast<bf16x8*>(&Ksm[row][seg * 8]) = kv;
            const __bf16* vp = vgl + (size_t)(t + row) * KVSZ + kvh * 64 + seg * 8;
            bf16x8 vv = *reinterpret_cast<const bf16x8*>(vp);
            #pragma unroll
            for (int e = 0; e < 8; e++) Vts[seg * 8 + e][row] = vv[e];
        }
        __syncthreads();

        // S = Q K^T  (16 q-rows x 32 keys per wave)
        f32x4 s[2];
        #pragma unroll
        for (int kgi = 0; kgi < 2; kgi++) {
            s[kgi] = (f32x4){0.f, 0.f, 0.f, 0.f};
            #pragma unroll
            for (int ss = 0; ss < 2; ss++) {
                bf16x8 kf = *reinterpret_cast<const bf16x8*>(&Ksm[kgi*16 + ll][ss*32 + lg*8]);
                s[kgi] = __builtin_amdgcn_mfma_f32_16x16x32_bf16(qf[ss], kf, s[kgi], 0, 0, 0);
            }
        }

        // online softmax (per q-row r; row spread across 16 lanes)
        float alpha[4];
        #pragma unroll
        for (int r = 0; r < 4; r++) {
            int qi = qrow_w + lg * 4 + r;
            int j0 = t + ll, j1 = t + 16 + ll;
            bool ok0 = (j0 <= qi) && (qi - j0 < WINDOW);
            bool ok1 = (j1 <= qi) && (qi - j1 < WINDOW);
            float v0 = s[0][r], v1 = s[1][r];
            float mv = fmaxf(ok0 ? v0 : -1e30f, ok1 ? v1 : -1e30f);
            #pragma unroll
            for (int off = 1; off < 16; off <<= 1) mv = fmaxf(mv, __shfl_xor(mv, off));
            float mn = fmaxf(m_run[r], mv);
            alpha[r] = __expf(m_run[r] - mn);
            m_run[r] = mn;
            float p0 = ok0 ? __expf(v0 - mn) : 0.f;
            float p1 = ok1 ? __expf(v1 - mn) : 0.f;
            float ts = p0 + p1;
            #pragma unroll
            for (int off = 1; off < 16; off <<= 1) ts += __shfl_xor(ts, off);
            l_run[r] = l_run[r] * alpha[r] + ts;
            Psm[wid][lg*4 + r][ll]      = (__bf16)p0;
            Psm[wid][lg*4 + r][16 + ll] = (__bf16)p1;
        }
        #pragma unroll
        for (int dn = 0; dn < 4; dn++)
            #pragma unroll
            for (int r = 0; r < 4; r++) o[dn][r] *= alpha[r];

        // PV: O += P[16x32] * V[32x64]
        bf16x8 pf = *reinterpret_cast<const bf16x8*>(&Psm[wid][ll][lg * 8]);
        #pragma unroll
        for (int dn = 0; dn < 4; dn++) {
            bf16x8 vf = *reinterpret_cast<const bf16x8*>(&Vts[dn*16 + ll][lg * 8]);
            o[dn] = __builtin_amdgcn_mfma_f32_16x16x32_bf16(pf, vf, o[dn], 0, 0, 0);
        }
        __syncthreads();
    }

    // epilogue
    #pragma unroll
    for (int r = 0; r < 4; r++) {
        float inv = 1.0f / l_run[r];
        int row = qrow_w + lg * 4 + r;
        #pragma unroll
        for (int dn = 0; dn < 4; dn++)
            og[(size_t)row * QSZ + h * 64 + dn * 16 + ll] = (__bf16)(o[dn][r] * inv);
    }
}

// ---------------- launch ----------------
extern "C" void kernel_launch(void* const* d_in, const int* in_sizes, int n_in,
                              void* d_out, int out_size, void* d_ws, size_t ws_size,
                              hipStream_t stream) {
    const int*   positions = (const int*)d_in[0];
    const float* hidden    = (const float*)d_in[1];
    const float* wqkv      = (const float*)d_in[2];
    const float* wo        = (const float*)d_in[3];
    float* out = (float*)d_out;

    char* ws = (char*)d_ws;
    __bf16* hidden_bf = (__bf16*)(ws);                       // 2048x2048
    __bf16* wqkv_t    = (__bf16*)(ws + 8388608);             // 2560x2048
    __bf16* wo_t      = (__bf16*)(ws + 18874368);            // 2048x2048
    __bf16* qkv_bf    = (__bf16*)(ws + 27262976);            // 2048x2560
    __bf16* q_bf      = (__bf16*)(ws + 37748736);            // 2048x2048
    __bf16* k_bf      = (__bf16*)(ws + 46137344);            // 2048x256
    __bf16* v_bf      = (__bf16*)(ws + 47185920);            // 2048x256
    __bf16* attn_bf   = (__bf16*)(ws + 48234496);            // 2048x2048

    // prep
    cvt_f32_bf16<<<dim3((T_SEQ * HIDDEN) / 4 / 256), dim3(256), 0, stream>>>(
        (const float4*)hidden, (bf16x4*)hidden_bf);
    transpose_f32_bf16<<<dim3(QKVN / 32, HIDDEN / 32), dim3(256), 0, stream>>>(
        wqkv, wqkv_t, HIDDEN, QKVN);
    transpose_f32_bf16<<<dim3(HIDDEN / 32, QSZ / 32), dim3(256), 0, stream>>>(
        wo, wo_t, QSZ, HIDDEN);

    // qkv = hidden @ wqkv
    gemm_bt<1><<<dim3(QKVN / 128, T_SEQ / 128), dim3(256), 0, stream>>>(
        hidden_bf, wqkv_t, (void*)qkv_bf, T_SEQ, QKVN, HIDDEN);

    // rope + split
    rope_split<<<dim3((T_SEQ * 1280) / 256), dim3(256), 0, stream>>>(
        qkv_bf, positions, q_bf, k_bf, v_bf);

    // attention
    attn_kernel<<<dim3(T_SEQ / 64, NH), dim3(256), 0, stream>>>(
        q_bf, k_bf, v_bf, attn_bf);

    // out = attn @ wo
    gemm_bt<0><<<dim3(HIDDEN / 128, T_SEQ / 128), dim3(256), 0, stream>>>(
        attn_bf, wo_t, (void*)out, T_SEQ, HIDDEN, QSZ);
}

// Round 2
// 169.676 us; speedup vs baseline: 1.3924x; 1.3924x over previous
//
#include <hip/hip_runtime.h>
#include <hip/hip_bf16.h>

// ---- types ----
typedef float  f32x4  __attribute__((ext_vector_type(4)));
typedef __bf16 bf16x8 __attribute__((ext_vector_type(8)));
typedef __bf16 bf16x4 __attribute__((ext_vector_type(4)));
typedef __bf16 bf16x2 __attribute__((ext_vector_type(2)));

#define T_SEQ   2048
#define HIDDEN  2048
#define NH      32
#define NKV     4
#define HD      64
#define QSZ     2048
#define KVSZ    256
#define QKVN    2560
#define WINDOW  1024
#define SCALE   0.125f

// ---------------- convert f32 -> bf16 (vectorized) ----------------
__global__ __launch_bounds__(256) void cvt_f32_bf16(const float4* __restrict__ in,
                                                    bf16x4* __restrict__ out) {
    int id = blockIdx.x * 256 + threadIdx.x;
    float4 v = in[id];
    bf16x4 o;
    o[0] = (__bf16)v.x; o[1] = (__bf16)v.y; o[2] = (__bf16)v.z; o[3] = (__bf16)v.w;
    out[id] = o;
}

// ---------------- transpose f32 [Rin][Cin] -> bf16 [Cin][Rin] ----------------
__global__ __launch_bounds__(256) void transpose_f32_bf16(const float* __restrict__ in,
                                                          __bf16* __restrict__ out,
                                                          int Rin, int Cin) {
    __shared__ float tile[32][33];
    int r = threadIdx.x >> 5;     // 0..7
    int c = threadIdx.x & 31;     // 0..31
    int ri = blockIdx.y * 32, ci = blockIdx.x * 32;
    #pragma unroll
    for (int i = 0; i < 4; i++)
        tile[r + i*8][c] = in[(size_t)(ri + r + i*8) * Cin + ci + c];
    __syncthreads();
    #pragma unroll
    for (int i = 0; i < 4; i++)
        out[(size_t)(ci + r + i*8) * Rin + ri + c] = (__bf16)tile[c][r + i*8];
}

// ---------------- transpose V slice of qkv (bf16): out vT[256][T] ----------------
__global__ __launch_bounds__(256) void vtrans_bf16(const __bf16* __restrict__ qkv,
                                                   __bf16* __restrict__ vT) {
    __shared__ __bf16 tile[32][34];
    int r = threadIdx.x >> 5;     // 0..7
    int c = threadIdx.x & 31;     // 0..31
    int ti = blockIdx.x * 32;     // token tile
    int di = blockIdx.y * 32;     // dim tile (0..255)
    #pragma unroll
    for (int i = 0; i < 4; i++)
        tile[r + i*8][c] = qkv[(size_t)(ti + r + i*8) * QKVN + (QSZ + KVSZ) + di + c];
    __syncthreads();
    #pragma unroll
    for (int i = 0; i < 4; i++)
        vT[(size_t)(di + r + i*8) * T_SEQ + ti + c] = tile[c][r + i*8];
}

// ---------------- GEMM: C[M][N] = A[M][K] * Bt[N][K]^T  (bf16 in, fp32 acc) ----------------
template<int WRITE_BF16>
__global__ __launch_bounds__(256) void gemm_bt(const __bf16* __restrict__ A,
                                               const __bf16* __restrict__ Bt,
                                               void* __restrict__ Cout,
                                               int M, int N, int K) {
    __shared__ __align__(16) __bf16 Asm[128][72];
    __shared__ __align__(16) __bf16 Bsm[128][72];
    const int tid = threadIdx.x;
    const int wid = tid >> 6;
    const int l   = tid & 63;
    const int lg  = l >> 4;       // 0..3
    const int ll  = l & 15;       // 0..15
    const int wm  = wid >> 1, wn = wid & 1;
    const int bm  = blockIdx.y * 128, bn = blockIdx.x * 128;

    f32x4 acc[4][4];
    #pragma unroll
    for (int i = 0; i < 4; i++)
        #pragma unroll
        for (int j = 0; j < 4; j++)
            acc[i][j] = (f32x4){0.f, 0.f, 0.f, 0.f};

    const int rowA = tid >> 3;    // 0..31
    const int segA = tid & 7;     // 0..7

    for (int k0 = 0; k0 < K; k0 += 64) {
        #pragma unroll
        for (int c = 0; c < 4; c++) {
            int row = c * 32 + rowA;
            bf16x8 av = *reinterpret_cast<const bf16x8*>(A  + (size_t)(bm + row) * K + k0 + segA * 8);
            *reinterpret_cast<bf16x8*>(&Asm[row][segA * 8]) = av;
            bf16x8 bv = *reinterpret_cast<const bf16x8*>(Bt + (size_t)(bn + row) * K + k0 + segA * 8);
            *reinterpret_cast<bf16x8*>(&Bsm[row][segA * 8]) = bv;
        }
        __syncthreads();
        #pragma unroll
        for (int ss = 0; ss < 2; ss++) {
            bf16x8 af[4], bfr[4];
            #pragma unroll
            for (int mi = 0; mi < 4; mi++)
                af[mi] = *reinterpret_cast<const bf16x8*>(&Asm[wm*64 + mi*16 + ll][ss*32 + lg*8]);
            #pragma unroll
            for (int ni = 0; ni < 4; ni++)
                bfr[ni] = *reinterpret_cast<const bf16x8*>(&Bsm[wn*64 + ni*16 + ll][ss*32 + lg*8]);
            #pragma unroll
            for (int mi = 0; mi < 4; mi++)
                #pragma unroll
                for (int ni = 0; ni < 4; ni++)
                    acc[mi][ni] = __builtin_amdgcn_mfma_f32_16x16x32_bf16(af[mi], bfr[ni], acc[mi][ni], 0, 0, 0);
        }
        __syncthreads();
    }

    #pragma unroll
    for (int mi = 0; mi < 4; mi++) {
        #pragma unroll
        for (int ni = 0; ni < 4; ni++) {
            #pragma unroll
            for (int r = 0; r < 4; r++) {
                int row = bm + wm*64 + mi*16 + lg*4 + r;
                int col = bn + wn*64 + ni*16 + ll;
                if (WRITE_BF16)
                    ((__bf16*)Cout)[(size_t)row * N + col] = (__bf16)acc[mi][ni][r];
                else
                    ((float*)Cout)[(size_t)row * N + col] = acc[mi][ni][r];
            }
        }
    }
}

// ---------------- RoPE + split qkv -> q(scaled), k ----------------
__global__ __launch_bounds__(256) void rope_split(const __bf16* __restrict__ qkv,
                                                  const int* __restrict__ pos,
                                                  __bf16* __restrict__ q,
                                                  __bf16* __restrict__ k) {
    int id = blockIdx.x * 256 + threadIdx.x;   // T_SEQ * 1152 total
    int row  = id / 1152;
    int slot = id % 1152;
    bool isq = slot < 1024;
    int s2 = isq ? slot : slot - 1024;
    int head = s2 >> 5, f = s2 & 31;
    const __bf16* src;
    __bf16* dst;
    if (isq) {
        src = qkv + (size_t)row * QKVN + head * 64 + f;
        dst = q   + (size_t)row * QSZ  + head * 64 + f;
    } else {
        src = qkv + (size_t)row * QKVN + QSZ + head * 64 + f;
        dst = k   + (size_t)row * KVSZ + head * 64 + f;
    }
    float x1 = (float)src[0], x2 = (float)src[32];
    float p = (float)pos[row];
    float ifr = powf(1.0e6f, -(float)f * (1.0f / 32.0f));
    float ang = p * ifr;
    float sn, cs;
    sincosf(ang, &sn, &cs);
    float o1 = x1 * cs - x2 * sn;
    float o2 = x2 * cs + x1 * sn;
    if (isq) { o1 *= SCALE; o2 *= SCALE; }
    dst[0]  = (__bf16)o1;
    dst[32] = (__bf16)o2;
}

// ---------------- sliding-window GQA flash attention (swapped QK^T) ----------------
// grid: (T/64, NH); block 256 = 4 waves; wave w handles q rows [qb*64+w*16, +16)
// KV tile = 64 keys. S^T = mfma(K_frag, Q_frag): lane owns q-row (ll), 16 keys in-register.
__global__ __launch_bounds__(256) void attn_kernel(const __bf16* __restrict__ qg,
                                                   const __bf16* __restrict__ kgl,
                                                   const __bf16* __restrict__ vTg,
                                                   __bf16* __restrict__ og) {
    const int qb  = blockIdx.x;
    const int h   = blockIdx.y;
    const int kvh = h >> 3;          // NH/NKV = 8
    const int tid = threadIdx.x;
    const int wid = tid >> 6;
    const int l   = tid & 63;
    const int lg  = l >> 4;          // 0..3
    const int ll  = l & 15;          // 0..15
    const int i0  = qb * 64;
    const int qw  = i0 + wid * 16;   // wave's first q row
    const int qi  = qw + ll;         // this lane's q row (S^T layout)

    __shared__ __align__(16) __bf16 Ksm[64][72];
    __shared__ __align__(16) __bf16 VTs[64][72];
    __shared__ __align__(16) __bf16 Psm[4][16][72];

    // Q fragment (B-operand for swapped QK^T): lane ll = q-row, lg*8+e = d
    bf16x8 qf[2];
    {
        const __bf16* qp = qg + (size_t)(qw + ll) * QSZ + h * 64 + lg * 8;
        qf[0] = *reinterpret_cast<const bf16x8*>(qp);
        qf[1] = *reinterpret_cast<const bf16x8*>(qp + 32);
    }

    f32x4 o[4];
    #pragma unroll
    for (int dn = 0; dn < 4; dn++) o[dn] = (f32x4){0.f, 0.f, 0.f, 0.f};
    float m_run = -1e30f, l_run = 0.f;   // per lane: q-row = ll

    int jlo = i0 - (WINDOW - 1); if (jlo < 0) jlo = 0;
    int t0 = jlo & ~63;
    int tend = i0 + 64;

    for (int t = t0; t < tend; t += 64) {
        // ---- stage K [64 keys][64 d] and V^T [64 d][64 keys] (72-padded) ----
        #pragma unroll
        for (int part = 0; part < 2; part++) {
            int slot = part * 256 + tid;      // 0..511
            int row = slot >> 3, seg = slot & 7;
            *reinterpret_cast<bf16x8*>(&Ksm[row][seg * 8]) =
                *reinterpret_cast<const bf16x8*>(kgl + (size_t)(t + row) * KVSZ + kvh * 64 + seg * 8);
            *reinterpret_cast<bf16x8*>(&VTs[row][seg * 8]) =
                *reinterpret_cast<const bf16x8*>(vTg + (size_t)(kvh * 64 + row) * T_SEQ + t + seg * 8);
        }
        __syncthreads();

        // wave-level activity: does [t, t+63] overlap this wave's key range?
        bool active = (t <= qw + 15) && (t + 63 >= qw - (WINDOW - 1));
        if (active) {
            // S^T: 4 key-subtiles of 16; lane holds (q-row=ll, key=t+kt*16+lg*4+r)
            f32x4 sT[4];
            #pragma unroll
            for (int kt = 0; kt < 4; kt++) {
                sT[kt] = (f32x4){0.f, 0.f, 0.f, 0.f};
                #pragma unroll
                for (int ss = 0; ss < 2; ss++) {
                    bf16x8 kf = *reinterpret_cast<const bf16x8*>(&Ksm[kt*16 + ll][ss*32 + lg*8]);
                    sT[kt] = __builtin_amdgcn_mfma_f32_16x16x32_bf16(kf, qf[ss], sT[kt], 0, 0, 0);
                }
            }

            bool full = (t + 63 <= qw) && (t >= qw + 15 - (WINDOW - 1));
            float mv = -1e30f;
            if (full) {
                #pragma unroll
                for (int kt = 0; kt < 4; kt++)
                    #pragma unroll
                    for (int r = 0; r < 4; r++) mv = fmaxf(mv, sT[kt][r]);
            } else {
                #pragma unroll
                for (int kt = 0; kt < 4; kt++)
                    #pragma unroll
                    for (int r = 0; r < 4; r++) {
                        int j = t + kt * 16 + lg * 4 + r;
                        bool ok = (j <= qi) && (qi - j < WINDOW);
                        sT[kt][r] = ok ? sT[kt][r] : -1e30f;
                        mv = fmaxf(mv, sT[kt][r]);
                    }
            }
            // reduce across the 4 lane-groups holding this q-row
            mv = fmaxf(mv, __shfl_xor(mv, 16));
            mv = fmaxf(mv, __shfl_xor(mv, 32));
            float mn = fmaxf(m_run, mv);
            float alpha = __expf(m_run - mn);
            m_run = mn;

            float ts = 0.f;
            #pragma unroll
            for (int kt = 0; kt < 4; kt++) {
                float p0, p1, p2, p3;
                if (full) {
                    p0 = __expf(sT[kt][0] - mn);
                    p1 = __expf(sT[kt][1] - mn);
                    p2 = __expf(sT[kt][2] - mn);
                    p3 = __expf(sT[kt][3] - mn);
                } else {
                    p0 = (sT[kt][0] > -1e29f) ? __expf(sT[kt][0] - mn) : 0.f;
                    p1 = (sT[kt][1] > -1e29f) ? __expf(sT[kt][1] - mn) : 0.f;
                    p2 = (sT[kt][2] > -1e29f) ? __expf(sT[kt][2] - mn) : 0.f;
                    p3 = (sT[kt][3] > -1e29f) ? __expf(sT[kt][3] - mn) : 0.f;
                }
                ts += (p0 + p1) + (p2 + p3);
                *reinterpret_cast<bf16x2*>(&Psm[wid][ll][kt*16 + lg*4])     = (bf16x2){(__bf16)p0, (__bf16)p1};
                *reinterpret_cast<bf16x2*>(&Psm[wid][ll][kt*16 + lg*4 + 2]) = (bf16x2){(__bf16)p2, (__bf16)p3};
            }
            ts += __shfl_xor(ts, 16);
            ts += __shfl_xor(ts, 32);
            l_run = l_run * alpha + ts;

            // broadcast alpha from S^T layout (q-row=ll) to O layout (q-row=lg*4+r)
            float a0 = __shfl(alpha, lg*4 + 0);
            float a1 = __shfl(alpha, lg*4 + 1);
            float a2 = __shfl(alpha, lg*4 + 2);
            float a3 = __shfl(alpha, lg*4 + 3);
            #pragma unroll
            for (int dn = 0; dn < 4; dn++) {
                o[dn][0] *= a0; o[dn][1] *= a1; o[dn][2] *= a2; o[dn][3] *= a3;
            }

            // PV: O[16q x 64d] += P[16q x 64k] * V[64k x 64d]
            #pragma unroll
            for (int kt2 = 0; kt2 < 2; kt2++) {
                bf16x8 pa = *reinterpret_cast<const bf16x8*>(&Psm[wid][ll][kt2*32 + lg*8]);
                #pragma unroll
                for (int dn = 0; dn < 4; dn++) {
                    bf16x8 vf = *reinterpret_cast<const bf16x8*>(&VTs[dn*16 + ll][kt2*32 + lg*8]);
                    o[dn] = __builtin_amdgcn_mfma_f32_16x16x32_bf16(pa, vf, o[dn], 0, 0, 0);
                }
            }
        }
        __syncthreads();
    }

    // epilogue: redistribute 1/l from q-row=ll layout to q-row=lg*4+r layout
    float linv = 1.0f / l_run;
    float i0v = __shfl(linv, lg*4 + 0);
    float i1v = __shfl(linv, lg*4 + 1);
    float i2v = __shfl(linv, lg*4 + 2);
    float i3v = __shfl(linv, lg*4 + 3);
    #pragma unroll
    for (int dn = 0; dn < 4; dn++) {
        og[(size_t)(qw + lg*4 + 0) * QSZ + h*64 + dn*16 + ll] = (__bf16)(o[dn][0] * i0v);
        og[(size_t)(qw + lg*4 + 1) * QSZ + h*64 + dn*16 + ll] = (__bf16)(o[dn][1] * i1v);
        og[(size_t)(qw + lg*4 + 2) * QSZ + h*64 + dn*16 + ll] = (__bf16)(o[dn][2] * i2v);
        og[(size_t)(qw + lg*4 + 3) * QSZ + h*64 + dn*16 + ll] = (__bf16)(o[dn][3] * i3v);
    }
}

// ---------------- launch ----------------
extern "C" void kernel_launch(void* const* d_in, const int* in_sizes, int n_in,
                              void* d_out, int out_size, void* d_ws, size_t ws_size,
                              hipStream_t stream) {
    const int*   positions = (const int*)d_in[0];
    const float* hidden    = (const float*)d_in[1];
    const float* wqkv      = (const float*)d_in[2];
    const float* wo        = (const float*)d_in[3];
    float* out = (float*)d_out;

    char* ws = (char*)d_ws;
    __bf16* hidden_bf = (__bf16*)(ws);                       // 2048x2048
    __bf16* wqkv_t    = (__bf16*)(ws + 8388608);             // 2560x2048
    __bf16* wo_t      = (__bf16*)(ws + 18874368);            // 2048x2048
    __bf16* qkv_bf    = (__bf16*)(ws + 27262976);            // 2048x2560
    __bf16* q_bf      = (__bf16*)(ws + 37748736);            // 2048x2048
    __bf16* k_bf      = (__bf16*)(ws + 46137344);            // 2048x256
    __bf16* vT_bf     = (__bf16*)(ws + 47185920);            // 256x2048 (V^T)
    __bf16* attn_bf   = (__bf16*)(ws + 48234496);            // 2048x2048

    cvt_f32_bf16<<<dim3((T_SEQ * HIDDEN) / 4 / 256), dim3(256), 0, stream>>>(
        (const float4*)hidden, (bf16x4*)hidden_bf);
    transpose_f32_bf16<<<dim3(QKVN / 32, HIDDEN / 32), dim3(256), 0, stream>>>(
        wqkv, wqkv_t, HIDDEN, QKVN);
    transpose_f32_bf16<<<dim3(HIDDEN / 32, QSZ / 32), dim3(256), 0, stream>>>(
        wo, wo_t, QSZ, HIDDEN);

    gemm_bt<1><<<dim3(QKVN / 128, T_SEQ / 128), dim3(256), 0, stream>>>(
        hidden_bf, wqkv_t, (void*)qkv_bf, T_SEQ, QKVN, HIDDEN);

    rope_split<<<dim3((T_SEQ * 1152) / 256), dim3(256), 0, stream>>>(
        qkv_bf, positions, q_bf, k_bf);
    vtrans_bf16<<<dim3(T_SEQ / 32, KVSZ / 32), dim3(256), 0, stream>>>(
        qkv_bf, vT_bf);

    attn_kernel<<<dim3(T_SEQ / 64, NH), dim3(256), 0, stream>>>(
        q_bf, k_bf, vT_bf, attn_bf);

    gemm_bt<0><<<dim3(HIDDEN / 128, T_SEQ / 128), dim3(256), 0, stream>>>(
        attn_bf, wo_t, (void*)out, T_SEQ, HIDDEN, QSZ);
}

// Round 3
// 154.242 us; speedup vs baseline: 1.5318x; 1.1001x over previous
//
#include <hip/hip_runtime.h>
#include <hip/hip_bf16.h>

// ---- types ----
typedef float  f32x4  __attribute__((ext_vector_type(4)));
typedef __bf16 bf16x8 __attribute__((ext_vector_type(8)));
typedef __bf16 bf16x4 __attribute__((ext_vector_type(4)));
typedef __bf16 bf16x2 __attribute__((ext_vector_type(2)));

#define T_SEQ   2048
#define HIDDEN  2048
#define NH      32
#define NKV     4
#define HD      64
#define QSZ     2048
#define KVSZ    256
#define QKVN    2560
#define WINDOW  1024
// SCALE * log2(e): scores computed in log2 domain
#define QSCALE  0.1803368801111f

__device__ __forceinline__ void gll16(const __bf16* g, __bf16* l) {
    __builtin_amdgcn_global_load_lds(
        (const __attribute__((address_space(1))) void*)g,
        (__attribute__((address_space(3))) void*)l,
        16, 0, 0);
}

// ---------------- convert f32 -> bf16 (vectorized) ----------------
__global__ __launch_bounds__(256) void cvt_f32_bf16(const float4* __restrict__ in,
                                                    bf16x4* __restrict__ out) {
    int id = blockIdx.x * 256 + threadIdx.x;
    float4 v = in[id];
    bf16x4 o;
    o[0] = (__bf16)v.x; o[1] = (__bf16)v.y; o[2] = (__bf16)v.z; o[3] = (__bf16)v.w;
    out[id] = o;
}

// ---------------- transpose f32 [Rin][Cin] -> bf16 [Cin][Rin] ----------------
__global__ __launch_bounds__(256) void transpose_f32_bf16(const float* __restrict__ in,
                                                          __bf16* __restrict__ out,
                                                          int Rin, int Cin) {
    __shared__ float tile[32][33];
    int r = threadIdx.x >> 5;
    int c = threadIdx.x & 31;
    int ri = blockIdx.y * 32, ci = blockIdx.x * 32;
    #pragma unroll
    for (int i = 0; i < 4; i++)
        tile[r + i*8][c] = in[(size_t)(ri + r + i*8) * Cin + ci + c];
    __syncthreads();
    #pragma unroll
    for (int i = 0; i < 4; i++)
        out[(size_t)(ci + r + i*8) * Rin + ri + c] = (__bf16)tile[c][r + i*8];
}

// ---------------- transpose V slice of qkv (bf16): out vT[256][T] ----------------
__global__ __launch_bounds__(256) void vtrans_bf16(const __bf16* __restrict__ qkv,
                                                   __bf16* __restrict__ vT) {
    __shared__ __bf16 tile[32][34];
    int r = threadIdx.x >> 5;
    int c = threadIdx.x & 31;
    int ti = blockIdx.x * 32;
    int di = blockIdx.y * 32;
    #pragma unroll
    for (int i = 0; i < 4; i++)
        tile[r + i*8][c] = qkv[(size_t)(ti + r + i*8) * QKVN + (QSZ + KVSZ) + di + c];
    __syncthreads();
    #pragma unroll
    for (int i = 0; i < 4; i++)
        vT[(size_t)(di + r + i*8) * T_SEQ + ti + c] = tile[c][r + i*8];
}

// ---------------- GEMM: C[M][N] = A[M][K] * Bt[N][K]^T ----------------
// global_load_lds staging (linear LDS, pre-swizzled source), 2-phase pipeline,
// XCD-bijective block swizzle. LDS fragment reads XOR-swizzled (unit ^= row&7).
template<int WRITE_BF16>
__global__ __launch_bounds__(256) void gemm_bt(const __bf16* __restrict__ A,
                                               const __bf16* __restrict__ Bt,
                                               void* __restrict__ Cout,
                                               int M, int N, int K) {
    __shared__ __align__(16) __bf16 Asm[2][128 * 64];
    __shared__ __align__(16) __bf16 Bsm[2][128 * 64];
    const int tid = threadIdx.x;
    const int wid = tid >> 6;
    const int l   = tid & 63;
    const int lg  = l >> 4;
    const int ll  = l & 15;
    const int swl = ll & 7;
    const int wm  = wid >> 1, wn = wid & 1;

    // XCD-bijective swizzle (nwg % 8 == 0 for all our grids)
    const int gx   = gridDim.x;
    const int flat = blockIdx.y * gx + blockIdx.x;
    const int nwg  = gx * gridDim.y;
    const int swz  = (flat & 7) * (nwg >> 3) + (flat >> 3);
    const int bm   = (swz / gx) * 128;
    const int bn   = (swz % gx) * 128;

    const __bf16* Ab = A  + (size_t)bm * K;
    const __bf16* Bb = Bt + (size_t)bn * K;

    f32x4 acc[4][4];
    #pragma unroll
    for (int i = 0; i < 4; i++)
        #pragma unroll
        for (int j = 0; j < 4; j++)
            acc[i][j] = (f32x4){0.f, 0.f, 0.f, 0.f};

    // staging geometry: slot = c*256 + tid; each slot = 16B = one row-unit.
    // LDS dest linear (slot*16B); global source unit pre-swizzled by row&7.
    const int srow = tid >> 3;                 // +c*32
    const int sseg0 = tid & 7;

#define STAGE(buf, k0)                                                          \
    {                                                                           \
        _Pragma("unroll")                                                       \
        for (int c = 0; c < 4; c++) {                                           \
            int row  = c * 32 + srow;                                           \
            int sseg = sseg0 ^ (row & 7);                                       \
            __bf16* ldb = &Asm[buf][(c * 256 + wid * 64) * 8];                  \
            gll16(Ab + (size_t)row * K + (k0) + sseg * 8, ldb);                 \
            __bf16* ldbB = &Bsm[buf][(c * 256 + wid * 64) * 8];                 \
            gll16(Bb + (size_t)row * K + (k0) + sseg * 8, ldbB);                \
        }                                                                       \
    }

    STAGE(0, 0);
    __syncthreads();

    int cur = 0;
    for (int k0 = 0; k0 < K; k0 += 64) {
        int nxt = k0 + 64;
        if (nxt < K) STAGE(cur ^ 1, nxt);

        #pragma unroll
        for (int ss = 0; ss < 2; ss++) {
            bf16x8 af[4], bfr[4];
            #pragma unroll
            for (int mi = 0; mi < 4; mi++) {
                int r = wm * 64 + mi * 16 + ll;
                int u = (ss * 4 + lg) ^ swl;
                af[mi] = *reinterpret_cast<const bf16x8*>(&Asm[cur][r * 64 + u * 8]);
            }
            #pragma unroll
            for (int ni = 0; ni < 4; ni++) {
                int r = wn * 64 + ni * 16 + ll;
                int u = (ss * 4 + lg) ^ swl;
                bfr[ni] = *reinterpret_cast<const bf16x8*>(&Bsm[cur][r * 64 + u * 8]);
            }
            #pragma unroll
            for (int mi = 0; mi < 4; mi++)
                #pragma unroll
                for (int ni = 0; ni < 4; ni++)
                    acc[mi][ni] = __builtin_amdgcn_mfma_f32_16x16x32_bf16(af[mi], bfr[ni], acc[mi][ni], 0, 0, 0);
        }
        __syncthreads();
        cur ^= 1;
    }
#undef STAGE

    #pragma unroll
    for (int mi = 0; mi < 4; mi++) {
        #pragma unroll
        for (int ni = 0; ni < 4; ni++) {
            #pragma unroll
            for (int r = 0; r < 4; r++) {
                int row = bm + wm*64 + mi*16 + lg*4 + r;
                int col = bn + wn*64 + ni*16 + ll;
                if (WRITE_BF16)
                    ((__bf16*)Cout)[(size_t)row * N + col] = (__bf16)acc[mi][ni][r];
                else
                    ((float*)Cout)[(size_t)row * N + col] = acc[mi][ni][r];
            }
        }
    }
}

// ---------------- RoPE + split qkv -> q(scaled, log2 domain), k ----------------
__global__ __launch_bounds__(256) void rope_split(const __bf16* __restrict__ qkv,
                                                  const int* __restrict__ pos,
                                                  __bf16* __restrict__ q,
                                                  __bf16* __restrict__ k) {
    int id = blockIdx.x * 256 + threadIdx.x;   // T_SEQ * 1152 total
    int row  = id / 1152;
    int slot = id % 1152;
    bool isq = slot < 1024;
    int s2 = isq ? slot : slot - 1024;
    int head = s2 >> 5, f = s2 & 31;
    const __bf16* src;
    __bf16* dst;
    if (isq) {
        src = qkv + (size_t)row * QKVN + head * 64 + f;
        dst = q   + (size_t)row * QSZ  + head * 64 + f;
    } else {
        src = qkv + (size_t)row * QKVN + QSZ + head * 64 + f;
        dst = k   + (size_t)row * KVSZ + head * 64 + f;
    }
    float x1 = (float)src[0], x2 = (float)src[32];
    float p = (float)pos[row];
    // 1e6^(-f/32) = 2^(-f * log2(1e6)/32)
    float ifr = exp2f((float)f * -0.62286151779138f);
    float ang = p * ifr;
    float sn, cs;
    sincosf(ang, &sn, &cs);
    float o1 = x1 * cs - x2 * sn;
    float o2 = x2 * cs + x1 * sn;
    if (isq) { o1 *= QSCALE; o2 *= QSCALE; }
    dst[0]  = (__bf16)o1;
    dst[32] = (__bf16)o2;
}

// ---------------- sliding-window GQA flash attention (swapped QK^T) ----------------
__global__ __launch_bounds__(256) void attn_kernel(const __bf16* __restrict__ qg,
                                                   const __bf16* __restrict__ kgl,
                                                   const __bf16* __restrict__ vTg,
                                                   __bf16* __restrict__ og) {
    const int qb  = blockIdx.x;
    const int h   = blockIdx.y;
    const int kvh = h >> 3;
    const int tid = threadIdx.x;
    const int wid = tid >> 6;
    const int l   = tid & 63;
    const int lg  = l >> 4;
    const int ll  = l & 15;
    const int i0  = qb * 64;
    const int qw  = i0 + wid * 16;
    const int qi  = qw + ll;

    __shared__ __align__(16) __bf16 Ksm[64][72];
    __shared__ __align__(16) __bf16 VTs[64][72];
    __shared__ __align__(16) __bf16 Psm[4][16][72];

    bf16x8 qf[2];
    {
        const __bf16* qp = qg + (size_t)(qw + ll) * QSZ + h * 64 + lg * 8;
        qf[0] = *reinterpret_cast<const bf16x8*>(qp);
        qf[1] = *reinterpret_cast<const bf16x8*>(qp + 32);
    }

    f32x4 o[4];
    #pragma unroll
    for (int dn = 0; dn < 4; dn++) o[dn] = (f32x4){0.f, 0.f, 0.f, 0.f};
    float m_run = -1e30f, l_run = 0.f;

    int jlo = i0 - (WINDOW - 1); if (jlo < 0) jlo = 0;
    int t0 = jlo & ~63;
    int tend = i0 + 64;

    for (int t = t0; t < tend; t += 64) {
        #pragma unroll
        for (int part = 0; part < 2; part++) {
            int slot = part * 256 + tid;
            int row = slot >> 3, seg = slot & 7;
            *reinterpret_cast<bf16x8*>(&Ksm[row][seg * 8]) =
                *reinterpret_cast<const bf16x8*>(kgl + (size_t)(t + row) * KVSZ + kvh * 64 + seg * 8);
            *reinterpret_cast<bf16x8*>(&VTs[row][seg * 8]) =
                *reinterpret_cast<const bf16x8*>(vTg + (size_t)(kvh * 64 + row) * T_SEQ + t + seg * 8);
        }
        __syncthreads();

        bool active = (t <= qw + 15) && (t + 63 >= qw - (WINDOW - 1));
        if (active) {
            f32x4 sT[4];
            #pragma unroll
            for (int kt = 0; kt < 4; kt++) {
                sT[kt] = (f32x4){0.f, 0.f, 0.f, 0.f};
                #pragma unroll
                for (int ss = 0; ss < 2; ss++) {
                    bf16x8 kf = *reinterpret_cast<const bf16x8*>(&Ksm[kt*16 + ll][ss*32 + lg*8]);
                    sT[kt] = __builtin_amdgcn_mfma_f32_16x16x32_bf16(kf, qf[ss], sT[kt], 0, 0, 0);
                }
            }

            bool full = (t + 63 <= qw) && (t >= qw + 15 - (WINDOW - 1));
            float mv = -1e30f;
            if (full) {
                #pragma unroll
                for (int kt = 0; kt < 4; kt++)
                    #pragma unroll
                    for (int r = 0; r < 4; r++) mv = fmaxf(mv, sT[kt][r]);
            } else {
                #pragma unroll
                for (int kt = 0; kt < 4; kt++)
                    #pragma unroll
                    for (int r = 0; r < 4; r++) {
                        int j = t + kt * 16 + lg * 4 + r;
                        bool ok = (j <= qi) && (qi - j < WINDOW);
                        sT[kt][r] = ok ? sT[kt][r] : -1e30f;
                        mv = fmaxf(mv, sT[kt][r]);
                    }
            }
            mv = fmaxf(mv, __shfl_xor(mv, 16));
            mv = fmaxf(mv, __shfl_xor(mv, 32));

            // T13 defer-max: skip rescale while tile max stays within 2^8 of running max
            if (!__all(mv - m_run <= 8.0f)) {
                float mn = fmaxf(m_run, mv);
                float alpha = exp2f(m_run - mn);
                m_run = mn;
                l_run *= alpha;
                float a0 = __shfl(alpha, lg*4 + 0);
                float a1 = __shfl(alpha, lg*4 + 1);
                float a2 = __shfl(alpha, lg*4 + 2);
                float a3 = __shfl(alpha, lg*4 + 3);
                #pragma unroll
                for (int dn = 0; dn < 4; dn++) {
                    o[dn][0] *= a0; o[dn][1] *= a1; o[dn][2] *= a2; o[dn][3] *= a3;
                }
            }

            float ts = 0.f;
            #pragma unroll
            for (int kt = 0; kt < 4; kt++) {
                float p0, p1, p2, p3;
                if (full) {
                    p0 = exp2f(sT[kt][0] - m_run);
                    p1 = exp2f(sT[kt][1] - m_run);
                    p2 = exp2f(sT[kt][2] - m_run);
                    p3 = exp2f(sT[kt][3] - m_run);
                } else {
                    p0 = (sT[kt][0] > -1e29f) ? exp2f(sT[kt][0] - m_run) : 0.f;
                    p1 = (sT[kt][1] > -1e29f) ? exp2f(sT[kt][1] - m_run) : 0.f;
                    p2 = (sT[kt][2] > -1e29f) ? exp2f(sT[kt][2] - m_run) : 0.f;
                    p3 = (sT[kt][3] > -1e29f) ? exp2f(sT[kt][3] - m_run) : 0.f;
                }
                ts += (p0 + p1) + (p2 + p3);
                *reinterpret_cast<bf16x2*>(&Psm[wid][ll][kt*16 + lg*4])     = (bf16x2){(__bf16)p0, (__bf16)p1};
                *reinterpret_cast<bf16x2*>(&Psm[wid][ll][kt*16 + lg*4 + 2]) = (bf16x2){(__bf16)p2, (__bf16)p3};
            }
            ts += __shfl_xor(ts, 16);
            ts += __shfl_xor(ts, 32);
            l_run += ts;

            #pragma unroll
            for (int kt2 = 0; kt2 < 2; kt2++) {
                bf16x8 pa = *reinterpret_cast<const bf16x8*>(&Psm[wid][ll][kt2*32 + lg*8]);
                #pragma unroll
                for (int dn = 0; dn < 4; dn++) {
                    bf16x8 vf = *reinterpret_cast<const bf16x8*>(&VTs[dn*16 + ll][kt2*32 + lg*8]);
                    o[dn] = __builtin_amdgcn_mfma_f32_16x16x32_bf16(pa, vf, o[dn], 0, 0, 0);
                }
            }
        }
        __syncthreads();
    }

    float linv = 1.0f / l_run;
    float i0v = __shfl(linv, lg*4 + 0);
    float i1v = __shfl(linv, lg*4 + 1);
    float i2v = __shfl(linv, lg*4 + 2);
    float i3v = __shfl(linv, lg*4 + 3);
    #pragma unroll
    for (int dn = 0; dn < 4; dn++) {
        og[(size_t)(qw + lg*4 + 0) * QSZ + h*64 + dn*16 + ll] = (__bf16)(o[dn][0] * i0v);
        og[(size_t)(qw + lg*4 + 1) * QSZ + h*64 + dn*16 + ll] = (__bf16)(o[dn][1] * i1v);
        og[(size_t)(qw + lg*4 + 2) * QSZ + h*64 + dn*16 + ll] = (__bf16)(o[dn][2] * i2v);
        og[(size_t)(qw + lg*4 + 3) * QSZ + h*64 + dn*16 + ll] = (__bf16)(o[dn][3] * i3v);
    }
}

// ---------------- launch ----------------
extern "C" void kernel_launch(void* const* d_in, const int* in_sizes, int n_in,
                              void* d_out, int out_size, void* d_ws, size_t ws_size,
                              hipStream_t stream) {
    const int*   positions = (const int*)d_in[0];
    const float* hidden    = (const float*)d_in[1];
    const float* wqkv      = (const float*)d_in[2];
    const float* wo        = (const float*)d_in[3];
    float* out = (float*)d_out;

    char* ws = (char*)d_ws;
    __bf16* hidden_bf = (__bf16*)(ws);                       // 2048x2048
    __bf16* wqkv_t    = (__bf16*)(ws + 8388608);             // 2560x2048
    __bf16* wo_t      = (__bf16*)(ws + 18874368);            // 2048x2048
    __bf16* qkv_bf    = (__bf16*)(ws + 27262976);            // 2048x2560
    __bf16* q_bf      = (__bf16*)(ws + 37748736);            // 2048x2048
    __bf16* k_bf      = (__bf16*)(ws + 46137344);            // 2048x256
    __bf16* vT_bf     = (__bf16*)(ws + 47185920);            // 256x2048 (V^T)
    __bf16* attn_bf   = (__bf16*)(ws + 48234496);            // 2048x2048

    cvt_f32_bf16<<<dim3((T_SEQ * HIDDEN) / 4 / 256), dim3(256), 0, stream>>>(
        (const float4*)hidden, (bf16x4*)hidden_bf);
    transpose_f32_bf16<<<dim3(QKVN / 32, HIDDEN / 32), dim3(256), 0, stream>>>(
        wqkv, wqkv_t, HIDDEN, QKVN);
    transpose_f32_bf16<<<dim3(HIDDEN / 32, QSZ / 32), dim3(256), 0, stream>>>(
        wo, wo_t, QSZ, HIDDEN);

    gemm_bt<1><<<dim3(QKVN / 128, T_SEQ / 128), dim3(256), 0, stream>>>(
        hidden_bf, wqkv_t, (void*)qkv_bf, T_SEQ, QKVN, HIDDEN);

    rope_split<<<dim3((T_SEQ * 1152) / 256), dim3(256), 0, stream>>>(
        qkv_bf, positions, q_bf, k_bf);
    vtrans_bf16<<<dim3(T_SEQ / 32, KVSZ / 32), dim3(256), 0, stream>>>(
        qkv_bf, vT_bf);

    attn_kernel<<<dim3(T_SEQ / 64, NH), dim3(256), 0, stream>>>(
        q_bf, k_bf, vT_bf, attn_bf);

    gemm_bt<0><<<dim3(HIDDEN / 128, T_SEQ / 128), dim3(256), 0, stream>>>(
        attn_bf, wo_t, (void*)out, T_SEQ, HIDDEN, QSZ);
}